// Round 10
// baseline (301.234 us; speedup 1.0000x reference)
//
#include <hip/hip_runtime.h>
#include <math.h>

#define B_ 4
#define N_ 2048
#define DIM_ 1024
#define H_ 16
#define D_ 64
#define INNER_ 1024
#define BH_ (B_*H_)

#define A_ELEMS  (B_*N_*INNER_)        // 8388608
#define M_ELEMS  (BH_*D_*D_)           // 262144
#define Z_ELEMS  (BH_*D_)              // 4096

#define SC_LOG2E 0.18033688011112042f  // 0.125 * log2(e)

typedef __attribute__((ext_vector_type(8))) short short8;
typedef __attribute__((ext_vector_type(4))) float f32x4;
typedef __attribute__((ext_vector_type(4))) unsigned short us4;
typedef unsigned short u16;

__device__ __forceinline__ u16 f2bf(float f) {
    unsigned int u = __float_as_uint(f);
    u += 0x7fffu + ((u >> 16) & 1u);          // round-to-nearest-even
    return (u16)(u >> 16);
}
__device__ __forceinline__ float bf2f(u16 s) {
    return __uint_as_float(((unsigned int)s) << 16);
}
__device__ __forceinline__ float sigma_f(float x) {
    return x > 0.f ? x + 1.f : __expf(x);     // elu(x)+1
}
__device__ __forceinline__ short8 sig8(short8 in) {
    short8 out;
    u16* ip = (u16*)&in; u16* op = (u16*)&out;
    #pragma unroll
    for (int c = 0; c < 8; c++) op[c] = f2bf(sigma_f(bf2f(ip[c])));
    return out;
}

// ---------------------------------------------------------------------------
// Kernel 0a: x (fp32) -> xb (bf16)
// ---------------------------------------------------------------------------
__global__ __launch_bounds__(256) void cvt_x(const float* __restrict__ x,
                                             u16* __restrict__ xb) {
    long i = ((long)blockIdx.x * 256 + threadIdx.x) * 4;
    float4 f = *(const float4*)&x[i];
    us4 o = {f2bf(f.x), f2bf(f.y), f2bf(f.z), f2bf(f.w)};
    *(us4*)&xb[i] = o;
}

// ---------------------------------------------------------------------------
// Kernel 0b: W [1024][3072] fp32 -> Wt [3072][1024] bf16 (transpose via LDS)
// ---------------------------------------------------------------------------
__global__ __launch_bounds__(256) void cvt_w(const float* __restrict__ W,
                                             u16* __restrict__ Wt) {
    __shared__ u16 T[64 * 68];
    const int t  = threadIdx.x;
    const int n0 = blockIdx.x * 64, k0 = blockIdx.y * 64;
    #pragma unroll
    for (int i = 0; i < 4; i++) {
        int r  = (t >> 4) + i * 16;
        int c4 = (t & 15) * 4;
        float4 f = *(const float4*)&W[(long)(k0 + r) * 3072 + n0 + c4];
        T[(c4 + 0) * 68 + r] = f2bf(f.x);
        T[(c4 + 1) * 68 + r] = f2bf(f.y);
        T[(c4 + 2) * 68 + r] = f2bf(f.z);
        T[(c4 + 3) * 68 + r] = f2bf(f.w);
    }
    __syncthreads();
    #pragma unroll
    for (int i = 0; i < 4; i++) {
        int n  = (t >> 4) + i * 16;
        int k4 = (t & 15) * 4;
        us4 o;
        o.x = T[n * 68 + k4];     o.y = T[n * 68 + k4 + 1];
        o.z = T[n * 68 + k4 + 2]; o.w = T[n * 68 + k4 + 3];
        *(us4*)&Wt[(long)(n0 + n) * 1024 + k0 + k4] = o;
    }
}

// ---------------------------------------------------------------------------
// Kernel 1: qkv = x @ W_qkv via bf16 MFMA; q,k,v row-major [bh][n][d].
// Also writes qs = q * (0.125*log2e) for flash (separate buffer).
// ---------------------------------------------------------------------------
__global__ __launch_bounds__(256) void qkv_mfma(
    const u16* __restrict__ xb, const u16* __restrict__ Wt,
    u16* __restrict__ q, u16* __restrict__ k, u16* __restrict__ v,
    u16* __restrict__ qs) {
    __shared__ u16 As[128 * 40];
    __shared__ u16 Bs[128 * 40];
    const int t = threadIdx.x, w = t >> 6, lane = t & 63;
    const int quad = lane >> 4, l16 = lane & 15;
    const int m0 = blockIdx.y * 128, j0 = blockIdx.x * 128;
    const int mw = (w >> 1) * 64, nw = (w & 1) * 64;

    f32x4 acc[4][4] = {};

    for (int k0 = 0; k0 < DIM_; k0 += 32) {
        __syncthreads();
        #pragma unroll
        for (int i = 0; i < 2; i++) {
            int r = (t >> 2) + i * 64, kg = (t & 3) * 8;
            *(short8*)&As[r * 40 + kg] =
                *(const short8*)&xb[(long)(m0 + r) * 1024 + k0 + kg];
            *(short8*)&Bs[r * 40 + kg] =
                *(const short8*)&Wt[(long)(j0 + r) * 1024 + k0 + kg];
        }
        __syncthreads();

        short8 af[4], bf[4];
        #pragma unroll
        for (int mt = 0; mt < 4; mt++)
            af[mt] = *(const short8*)&As[(mw + mt * 16 + l16) * 40 + quad * 8];
        #pragma unroll
        for (int nt = 0; nt < 4; nt++)
            bf[nt] = *(const short8*)&Bs[(nw + nt * 16 + l16) * 40 + quad * 8];
        #pragma unroll
        for (int mt = 0; mt < 4; mt++)
            #pragma unroll
            for (int nt = 0; nt < 4; nt++)
                acc[mt][nt] = __builtin_amdgcn_mfma_f32_16x16x32_bf16(
                    af[mt], bf[nt], acc[mt][nt], 0, 0, 0);
    }

    #pragma unroll
    for (int mt = 0; mt < 4; mt++) {
        #pragma unroll
        for (int r = 0; r < 4; r++) {
            int mm = m0 + mw + mt * 16 + quad * 4 + r;
            int b  = mm >> 11, n = mm & 2047;
            #pragma unroll
            for (int nt = 0; nt < 4; nt++) {
                int col   = j0 + nw + nt * 16 + l16;
                int which = col >> 10;
                int rem   = col & 1023;
                int h = rem >> 6, d = rem & 63;
                long idx = (((long)(b * H_ + h)) * N_ + n) * D_ + d;
                float a = acc[mt][nt][r];
                u16 val = f2bf(a);
                if (which == 0) {
                    q[idx]  = val;
                    qs[idx] = f2bf(a * SC_LOG2E);
                } else {
                    u16* dst = (which == 1) ? k : v;
                    dst[idx] = val;
                }
            }
        }
    }
}

// ---------------------------------------------------------------------------
// Kernel 1b: vb [bh][n][d] -> vT [bh][d][n] (LDS transpose, XOR swizzle)
// ---------------------------------------------------------------------------
__global__ __launch_bounds__(256) void vt_transpose(
    const u16* __restrict__ vb, u16* __restrict__ vT) {
    __shared__ u16 T[64 * 72];
    const int bh = blockIdx.y;
    const int n0 = blockIdx.x * 64;
    const int t  = threadIdx.x;
    const int jj = t >> 3, kg = (t & 7) * 8;
    #pragma unroll
    for (int i = 0; i < 2; i++) {
        int j = jj + i * 32;
        short8 vv = *(const short8*)&vb[(((long)bh * N_ + n0 + j) << 6) + kg];
        u16* vp = (u16*)&vv;
        int jc = j ^ kg;
        #pragma unroll
        for (int c = 0; c < 8; c++) T[(kg + c) * 72 + jc] = vp[c];
    }
    __syncthreads();
    const int d = t >> 2, sg = (t & 3) * 16, xr = d & 56;
    short8 a0 = *(const short8*)&T[d * 72 + (sg ^ xr)];
    short8 a1 = *(const short8*)&T[d * 72 + ((sg + 8) ^ xr)];
    u16* dst = vT + ((long)bh * 64 + d) * 2048 + n0 + sg;
    *(short8*)dst       = a0;
    *(short8*)(dst + 8) = a1;
}

// ---------------------------------------------------------------------------
// Kernel 2: out_M = beta*M, out_Z = beta*Z
// ---------------------------------------------------------------------------
__global__ __launch_bounds__(256) void init_mz(
    const float* __restrict__ M, const float* __restrict__ Z,
    const float* __restrict__ beta_lin,
    float* __restrict__ outM, float* __restrict__ outZ) {
    float beta = 1.f / (1.f + __expf(-beta_lin[0]));
    beta = fminf(fmaxf(beta, 0.9f), 0.999f);
    int i = blockIdx.x * 256 + threadIdx.x;
    if (i < M_ELEMS) outM[i] = beta * M[i];
    if (i < Z_ELEMS) outZ[i] = beta * Z[i];
}

// ---------------------------------------------------------------------------
// Kernel 3: linear-attention branch via MFMA (unchanged).
// ---------------------------------------------------------------------------
__global__ __launch_bounds__(256) void linear_mfma(
    const u16* __restrict__ qg, const u16* __restrict__ kg_,
    const u16* __restrict__ vTg, const float* __restrict__ Mg,
    const float* __restrict__ Zg, const float* __restrict__ beta_gate,
    float* __restrict__ outA, float* __restrict__ outM, float* __restrict__ outZ) {
    __shared__ u16 MTz[80 * 72];
    __shared__ u16 sqsh[64 * 72];
    __shared__ u16 sksh[64 * 72];
    __shared__ u16 skT[64 * 72];
    __shared__ u16 vT[64 * 72];
    __shared__ u16 vmT[80 * 72];
    __shared__ float dks[64];

    const int bh = blockIdx.y, b = bh >> 4, h = bh & 15;
    const int t = threadIdx.x, w = t >> 6, lane = t & 63;
    const int quad = lane >> 4, l16 = lane & 15;
    const long bhN = (long)bh * N_;

    #pragma unroll
    for (int i = 0; i < 4; i++) {
        int d  = (t >> 4) + i * 16;
        int c4 = (t & 15) * 4;
        float4 f = *(const float4*)&Mg[bh * 4096 + d * 64 + c4];
        MTz[(c4 + 0) * 72 + d] = f2bf(f.x);
        MTz[(c4 + 1) * 72 + d] = f2bf(f.y);
        MTz[(c4 + 2) * 72 + d] = f2bf(f.z);
        MTz[(c4 + 3) * 72 + d] = f2bf(f.w);
    }
    if (t < 64) {
        MTz[64 * 72 + t] = f2bf(Zg[bh * 64 + t]);
        vmT[64 * 72 + t] = f2bf(1.0f);
    }
    for (int e = t; e < 15 * 72; e += 256) {
        MTz[65 * 72 + e] = 0;
        vmT[65 * 72 + e] = 0;
    }
    if (t >= 64 && t < 72) { MTz[64 * 72 + t] = 0; vmT[64 * 72 + t] = 0; }

    const float g = 1.f / (1.f + __expf(-beta_gate[h]));

    f32x4 macc[5] = {};

    const int jj = t >> 3;
    const int kgp = (t & 7) * 8;
    const int srow = t >> 2;
    const int sg   = (t & 3) * 16;

    for (int c0 = 0; c0 < 256; c0 += 64) {
        const int n0c = blockIdx.x * 256 + c0;
        __syncthreads();

        #pragma unroll
        for (int i = 0; i < 2; i++) {
            int j = jj + i * 32;
            long gb = ((bhN + n0c + j) << 6) + kgp;
            short8 q8 = sig8(*(const short8*)&qg[gb]);
            short8 k8 = sig8(*(const short8*)&kg_[gb]);
            *(short8*)&sqsh[j * 72 + kgp] = q8;
            *(short8*)&sksh[j * 72 + kgp] = k8;
            u16* kp = (u16*)&k8;
            int jc = j ^ kgp;
            #pragma unroll
            for (int c = 0; c < 8; c++) skT[(kgp + c) * 72 + jc] = kp[c];
        }
        {
            const u16* vp = vTg + ((long)bh * 64 + srow) * 2048 + n0c + sg;
            *(short8*)&vT[srow * 72 + sg]     = *(const short8*)vp;
            *(short8*)&vT[srow * 72 + sg + 8] = *(const short8*)(vp + 8);
        }
        __syncthreads();

        // --- MFMA1: A_raw = sq @ MTz ---
        {
            short8 a0 = *(const short8*)&sqsh[(w * 16 + l16) * 72 + quad * 8];
            short8 a1 = *(const short8*)&sqsh[(w * 16 + l16) * 72 + 32 + quad * 8];
            f32x4 am[5];
            #pragma unroll
            for (int ct = 0; ct < 5; ct++) {
                short8 b0 = *(const short8*)&MTz[(ct * 16 + l16) * 72 + quad * 8];
                short8 b1 = *(const short8*)&MTz[(ct * 16 + l16) * 72 + 32 + quad * 8];
                f32x4 acc = {};
                acc = __builtin_amdgcn_mfma_f32_16x16x32_bf16(a0, b0, acc, 0, 0, 0);
                acc = __builtin_amdgcn_mfma_f32_16x16x32_bf16(a1, b1, acc, 0, 0, 0);
                am[ct] = acc;
            }
            #pragma unroll
            for (int r = 0; r < 4; r++) {
                float dq  = __shfl(am[4][r], lane & 48, 64);
                float inv = __builtin_amdgcn_rcpf(dq);
                int n = n0c + w * 16 + quad * 4 + r;
                long row = ((long)(b * N_ + n)) * INNER_ + h * 64;
                #pragma unroll
                for (int ct = 0; ct < 4; ct++)
                    outA[row + ct * 16 + l16] = g * am[ct][r] * inv;
            }
        }

        // --- MFMA2: momentT = MTz @ sk ---
        f32x4 mt_[4];
        {
            short8 a0 = *(const short8*)&MTz[(w * 16 + l16) * 72 + quad * 8];
            short8 a1 = *(const short8*)&MTz[(w * 16 + l16) * 72 + 32 + quad * 8];
            #pragma unroll
            for (int ct = 0; ct < 4; ct++) {
                short8 b0 = *(const short8*)&sksh[(ct * 16 + l16) * 72 + quad * 8];
                short8 b1 = *(const short8*)&sksh[(ct * 16 + l16) * 72 + 32 + quad * 8];
                f32x4 acc = {};
                acc = __builtin_amdgcn_mfma_f32_16x16x32_bf16(a0, b0, acc, 0, 0, 0);
                acc = __builtin_amdgcn_mfma_f32_16x16x32_bf16(a1, b1, acc, 0, 0, 0);
                mt_[ct] = acc;
            }
            short8 z0 = *(const short8*)&MTz[(64 + l16) * 72 + quad * 8];
            short8 z1 = *(const short8*)&MTz[(64 + l16) * 72 + 32 + quad * 8];
            short8 b0 = *(const short8*)&sksh[(w * 16 + l16) * 72 + quad * 8];
            short8 b1 = *(const short8*)&sksh[(w * 16 + l16) * 72 + 32 + quad * 8];
            f32x4 acc = {};
            acc = __builtin_amdgcn_mfma_f32_16x16x32_bf16(z0, b0, acc, 0, 0, 0);
            acc = __builtin_amdgcn_mfma_f32_16x16x32_bf16(z1, b1, acc, 0, 0, 0);
            if (quad == 0) dks[w * 16 + l16] = __builtin_amdgcn_rcpf(acc[0]);
        }
        __syncthreads();

        // --- vmT = vT - momentT/dk (bf16) ---
        #pragma unroll
        for (int ct = 0; ct < 4; ct++) {
            float invdk = dks[ct * 16 + l16];
            #pragma unroll
            for (int r = 0; r < 4; r++) {
                int vd = w * 16 + quad * 4 + r;
                float vv = bf2f(vT[vd * 72 + ct * 16 + l16]);
                vmT[vd * 72 + ct * 16 + l16] = f2bf(vv - mt_[ct][r] * invdk);
            }
        }
        __syncthreads();

        // --- MFMA3: Macc += skT @ [vm | 1] ---
        {
            int drow = w * 16 + l16, xr = drow & 56;
            short8 a0 = *(const short8*)&skT[drow * 72 + ((quad * 8) ^ xr)];
            short8 a1 = *(const short8*)&skT[drow * 72 + ((32 + quad * 8) ^ xr)];
            #pragma unroll
            for (int ct = 0; ct < 5; ct++) {
                short8 b0 = *(const short8*)&vmT[(ct * 16 + l16) * 72 + quad * 8];
                short8 b1 = *(const short8*)&vmT[(ct * 16 + l16) * 72 + 32 + quad * 8];
                macc[ct] = __builtin_amdgcn_mfma_f32_16x16x32_bf16(a0, b0, macc[ct], 0, 0, 0);
                macc[ct] = __builtin_amdgcn_mfma_f32_16x16x32_bf16(a1, b1, macc[ct], 0, 0, 0);
            }
        }
    }

    #pragma unroll
    for (int ct = 0; ct < 4; ct++)
        #pragma unroll
        for (int r = 0; r < 4; r++) {
            int d = w * 16 + quad * 4 + r;
            atomicAdd(&outM[bh * 4096 + d * 64 + ct * 16 + l16], macc[ct][r]);
        }
    if (l16 == 0)
        #pragma unroll
        for (int r = 0; r < 4; r++)
            atomicAdd(&outZ[bh * 64 + w * 16 + quad * 4 + r], macc[4][r]);
}

// ---------------------------------------------------------------------------
// Kernel 4: flash attention (banked 116us structure + 2 VALU cuts):
//  - Q pre-scaled by 0.125*log2e (qs buffer) -> exp2 directly on S.
//  - l computed on the MFMA pipe via constant-ones B-frag; no shuffles.
// ---------------------------------------------------------------------------
__global__ __launch_bounds__(256) void flash_mfma(
    const u16* __restrict__ qsb, const u16* __restrict__ kb,
    const u16* __restrict__ vTg, const float* __restrict__ beta_gate,
    float* __restrict__ outA) {
    __shared__ u16 Ks[64 * 72];        // [key][d]
    __shared__ u16 Vt[64 * 72];        // [d][key]
    __shared__ u16 Ps[4][32 * 72];     // per-wave P [row][key]

    const int bh = blockIdx.y, b = bh >> 4, h = bh & 15;
    const int n0 = blockIdx.x * 128;
    const int t = threadIdx.x, w = t >> 6, lane = t & 63;
    const int quad = lane >> 4, l16 = lane & 15;
    const long bhN = (long)bh * N_;

    const int srow = t >> 2;           // 0..63
    const int sg   = (t & 3) * 16;
    const u16* kbase  = kb + (bhN << 6);
    const u16* vtbase = vTg + (long)bh * 64 * 2048;

    short8 qf[2][2];
    #pragma unroll
    for (int mi = 0; mi < 2; mi++) {
        long qrow = bhN + n0 + w * 32 + mi * 16 + l16;
        qf[mi][0] = *(const short8*)&qsb[(qrow << 6) + quad * 8];
        qf[mi][1] = *(const short8*)&qsb[(qrow << 6) + 32 + quad * 8];
    }

    const short8 onesf = {0x3F80, 0x3F80, 0x3F80, 0x3F80,
                          0x3F80, 0x3F80, 0x3F80, 0x3F80};  // bf16 1.0 x8

    // prefetch tile 0
    short8 kr0, kr1, vr0, vr1;
    {
        const u16* kp = kbase + ((long)srow << 6) + sg;
        kr0 = *(const short8*)kp;
        kr1 = *(const short8*)(kp + 8);
        const u16* vp = vtbase + (long)srow * 2048 + sg;
        vr0 = *(const short8*)vp;
        vr1 = *(const short8*)(vp + 8);
    }

    f32x4 of[2][4] = {};
    f32x4 ol[2] = {};

    for (int j0 = 0; j0 < N_; j0 += 64) {
        __syncthreads();
        *(short8*)&Ks[srow * 72 + sg]     = kr0;
        *(short8*)&Ks[srow * 72 + sg + 8] = kr1;
        *(short8*)&Vt[srow * 72 + sg]     = vr0;
        *(short8*)&Vt[srow * 72 + sg + 8] = vr1;
        __syncthreads();

        if (j0 + 64 < N_) {   // prefetch next tile during compute
            const u16* kp = kbase + ((long)(j0 + 64 + srow) << 6) + sg;
            kr0 = *(const short8*)kp;
            kr1 = *(const short8*)(kp + 8);
            const u16* vp = vtbase + (long)srow * 2048 + j0 + 64 + sg;
            vr0 = *(const short8*)vp;
            vr1 = *(const short8*)(vp + 8);
        }

        // S^T = K Qs^T per 16-key tile; p = exp2(s) (scale pre-folded into Q)
        #pragma unroll
        for (int kt = 0; kt < 4; kt++) {
            short8 kf0 = *(const short8*)&Ks[(kt * 16 + l16) * 72 + quad * 8];
            short8 kf1 = *(const short8*)&Ks[(kt * 16 + l16) * 72 + 32 + quad * 8];
            #pragma unroll
            for (int mi = 0; mi < 2; mi++) {
                f32x4 st = {};
                st = __builtin_amdgcn_mfma_f32_16x16x32_bf16(kf0, qf[mi][0], st, 0, 0, 0);
                st = __builtin_amdgcn_mfma_f32_16x16x32_bf16(kf1, qf[mi][1], st, 0, 0, 0);
                float p0 = __builtin_amdgcn_exp2f(st[0]);
                float p1 = __builtin_amdgcn_exp2f(st[1]);
                float p2 = __builtin_amdgcn_exp2f(st[2]);
                float p3 = __builtin_amdgcn_exp2f(st[3]);
                uint2 pk;
                pk.x = __builtin_amdgcn_perm(__float_as_uint(p1), __float_as_uint(p0),
                                             0x07060302u);
                pk.y = __builtin_amdgcn_perm(__float_as_uint(p3), __float_as_uint(p2),
                                             0x07060302u);
                *(uint2*)&Ps[w][(mi * 16 + l16) * 72 + kt * 16 + quad * 4] = pk;
            }
        }

        // O += P V ; l += P 1 (ones B-frag, MFMA pipe, no LDS read)
        #pragma unroll
        for (int s = 0; s < 2; s++) {
            short8 af0 = *(const short8*)&Ps[w][(l16) * 72 + s * 32 + quad * 8];
            short8 af1 = *(const short8*)&Ps[w][(16 + l16) * 72 + s * 32 + quad * 8];
            ol[0] = __builtin_amdgcn_mfma_f32_16x16x32_bf16(af0, onesf, ol[0], 0, 0, 0);
            ol[1] = __builtin_amdgcn_mfma_f32_16x16x32_bf16(af1, onesf, ol[1], 0, 0, 0);
            #pragma unroll
            for (int nt = 0; nt < 4; nt++) {
                short8 vf = *(const short8*)&Vt[(nt * 16 + l16) * 72 + s * 32 + quad * 8];
                of[0][nt] = __builtin_amdgcn_mfma_f32_16x16x32_bf16(af0, vf, of[0][nt], 0, 0, 0);
                of[1][nt] = __builtin_amdgcn_mfma_f32_16x16x32_bf16(af1, vf, of[1][nt], 0, 0, 0);
            }
        }
    }

    const float g  = 1.f / (1.f + __expf(-beta_gate[h]));
    const float gi = 1.f - g;
    #pragma unroll
    for (int mi = 0; mi < 2; mi++) {
        #pragma unroll
        for (int r = 0; r < 4; r++) {
            // ol[mi][r] = l for Q-row mi*16+quad*4+r (C/D row = quad*4+r)
            float sc = gi / ol[mi][r];
            int n = n0 + w * 32 + mi * 16 + quad * 4 + r;
            #pragma unroll
            for (int nt = 0; nt < 4; nt++) {
                long idx = ((long)(b * N_ + n)) * INNER_ + h * 64 + nt * 16 + l16;
                outA[idx] += sc * of[mi][nt][r];
            }
        }
    }
}

extern "C" void kernel_launch(void* const* d_in, const int* in_sizes, int n_in,
                              void* d_out, int out_size, void* d_ws, size_t ws_size,
                              hipStream_t stream) {
    const float* x         = (const float*)d_in[0];
    const float* M         = (const float*)d_in[1];
    const float* Z         = (const float*)d_in[2];
    const float* W         = (const float*)d_in[3];
    const float* beta_lin  = (const float*)d_in[4];
    const float* beta_gate = (const float*)d_in[5];

    float* out  = (float*)d_out;
    float* outA = out;
    float* outM = out + A_ELEMS;
    float* outZ = out + A_ELEMS + M_ELEMS;

    u16* xb = (u16*)d_ws;                         // [8192][1024]
    u16* Wt = xb + (size_t)8192 * 1024;           // [3072][1024]
    u16* qb = Wt + (size_t)3072 * 1024;           // [bh][n][d]
    u16* kb = qb + (size_t)BH_ * N_ * D_;         // [bh][n][d]
    u16* vb = kb + (size_t)BH_ * N_ * D_;         // [bh][n][d]
    u16* vt = vb + (size_t)BH_ * N_ * D_;         // [bh][d][n]
    u16* qs = vt + (size_t)BH_ * N_ * D_;         // [bh][n][d] pre-scaled q

    cvt_x<<<dim3(A_ELEMS / 1024), 256, 0, stream>>>(x, xb);
    cvt_w<<<dim3(48, 16), 256, 0, stream>>>(W, Wt);
    qkv_mfma<<<dim3(24, 64), 256, 0, stream>>>(xb, Wt, qb, kb, vb, qs);
    vt_transpose<<<dim3(N_ / 64, BH_), 256, 0, stream>>>(vb, vt);
    init_mz<<<dim3((M_ELEMS + 255) / 256), 256, 0, stream>>>(M, Z, beta_lin, outM, outZ);
    linear_mfma<<<dim3(8, BH_), 256, 0, stream>>>(qb, kb, vt, M, Z, beta_gate,
                                                  outA, outM, outZ);
    flash_mfma<<<dim3(N_ / 128, BH_), 256, 0, stream>>>(qs, kb, vt, beta_gate, outA);
}

// Round 11
// 294.929 us; speedup vs baseline: 1.0214x; 1.0214x over previous
//
#include <hip/hip_runtime.h>
#include <math.h>

#define B_ 4
#define N_ 2048
#define DIM_ 1024
#define H_ 16
#define D_ 64
#define INNER_ 1024
#define BH_ (B_*H_)

#define A_ELEMS  (B_*N_*INNER_)        // 8388608
#define M_ELEMS  (BH_*D_*D_)           // 262144
#define Z_ELEMS  (BH_*D_)              // 4096

#define SC_LOG2E 0.18033688011112042f  // 0.125 * log2(e)

typedef __attribute__((ext_vector_type(8))) short short8;
typedef __attribute__((ext_vector_type(4))) float f32x4;
typedef __attribute__((ext_vector_type(4))) unsigned short us4;
typedef unsigned short u16;

__device__ __forceinline__ u16 f2bf(float f) {
    unsigned int u = __float_as_uint(f);
    u += 0x7fffu + ((u >> 16) & 1u);          // round-to-nearest-even
    return (u16)(u >> 16);
}
__device__ __forceinline__ float bf2f(u16 s) {
    return __uint_as_float(((unsigned int)s) << 16);
}
__device__ __forceinline__ float sigma_f(float x) {
    return x > 0.f ? x + 1.f : __expf(x);     // elu(x)+1
}
__device__ __forceinline__ short8 sig8(short8 in) {
    short8 out;
    u16* ip = (u16*)&in; u16* op = (u16*)&out;
    #pragma unroll
    for (int c = 0; c < 8; c++) op[c] = f2bf(sigma_f(bf2f(ip[c])));
    return out;
}

// ---------------------------------------------------------------------------
// Kernel 0a: x (fp32) -> xb (bf16)
// ---------------------------------------------------------------------------
__global__ __launch_bounds__(256) void cvt_x(const float* __restrict__ x,
                                             u16* __restrict__ xb) {
    long i = ((long)blockIdx.x * 256 + threadIdx.x) * 4;
    float4 f = *(const float4*)&x[i];
    us4 o = {f2bf(f.x), f2bf(f.y), f2bf(f.z), f2bf(f.w)};
    *(us4*)&xb[i] = o;
}

// ---------------------------------------------------------------------------
// Kernel 0b: W [1024][3072] fp32 -> Wt [3072][1024] bf16 (transpose via LDS)
// ---------------------------------------------------------------------------
__global__ __launch_bounds__(256) void cvt_w(const float* __restrict__ W,
                                             u16* __restrict__ Wt) {
    __shared__ u16 T[64 * 68];
    const int t  = threadIdx.x;
    const int n0 = blockIdx.x * 64, k0 = blockIdx.y * 64;
    #pragma unroll
    for (int i = 0; i < 4; i++) {
        int r  = (t >> 4) + i * 16;
        int c4 = (t & 15) * 4;
        float4 f = *(const float4*)&W[(long)(k0 + r) * 3072 + n0 + c4];
        T[(c4 + 0) * 68 + r] = f2bf(f.x);
        T[(c4 + 1) * 68 + r] = f2bf(f.y);
        T[(c4 + 2) * 68 + r] = f2bf(f.z);
        T[(c4 + 3) * 68 + r] = f2bf(f.w);
    }
    __syncthreads();
    #pragma unroll
    for (int i = 0; i < 4; i++) {
        int n  = (t >> 4) + i * 16;
        int k4 = (t & 15) * 4;
        us4 o;
        o.x = T[n * 68 + k4];     o.y = T[n * 68 + k4 + 1];
        o.z = T[n * 68 + k4 + 2]; o.w = T[n * 68 + k4 + 3];
        *(us4*)&Wt[(long)(n0 + n) * 1024 + k0 + k4] = o;
    }
}

// ---------------------------------------------------------------------------
// Kernel 1: qkv = x @ W_qkv via bf16 MFMA; q,k,v row-major [bh][n][d].
// Also writes qs = q * (0.125*log2e) for flash (separate buffer).
// ---------------------------------------------------------------------------
__global__ __launch_bounds__(256) void qkv_mfma(
    const u16* __restrict__ xb, const u16* __restrict__ Wt,
    u16* __restrict__ q, u16* __restrict__ k, u16* __restrict__ v,
    u16* __restrict__ qs) {
    __shared__ u16 As[128 * 40];
    __shared__ u16 Bs[128 * 40];
    const int t = threadIdx.x, w = t >> 6, lane = t & 63;
    const int quad = lane >> 4, l16 = lane & 15;
    const int m0 = blockIdx.y * 128, j0 = blockIdx.x * 128;
    const int mw = (w >> 1) * 64, nw = (w & 1) * 64;

    f32x4 acc[4][4] = {};

    for (int k0 = 0; k0 < DIM_; k0 += 32) {
        __syncthreads();
        #pragma unroll
        for (int i = 0; i < 2; i++) {
            int r = (t >> 2) + i * 64, kg = (t & 3) * 8;
            *(short8*)&As[r * 40 + kg] =
                *(const short8*)&xb[(long)(m0 + r) * 1024 + k0 + kg];
            *(short8*)&Bs[r * 40 + kg] =
                *(const short8*)&Wt[(long)(j0 + r) * 1024 + k0 + kg];
        }
        __syncthreads();

        short8 af[4], bf[4];
        #pragma unroll
        for (int mt = 0; mt < 4; mt++)
            af[mt] = *(const short8*)&As[(mw + mt * 16 + l16) * 40 + quad * 8];
        #pragma unroll
        for (int nt = 0; nt < 4; nt++)
            bf[nt] = *(const short8*)&Bs[(nw + nt * 16 + l16) * 40 + quad * 8];
        #pragma unroll
        for (int mt = 0; mt < 4; mt++)
            #pragma unroll
            for (int nt = 0; nt < 4; nt++)
                acc[mt][nt] = __builtin_amdgcn_mfma_f32_16x16x32_bf16(
                    af[mt], bf[nt], acc[mt][nt], 0, 0, 0);
    }

    #pragma unroll
    for (int mt = 0; mt < 4; mt++) {
        #pragma unroll
        for (int r = 0; r < 4; r++) {
            int mm = m0 + mw + mt * 16 + quad * 4 + r;
            int b  = mm >> 11, n = mm & 2047;
            #pragma unroll
            for (int nt = 0; nt < 4; nt++) {
                int col   = j0 + nw + nt * 16 + l16;
                int which = col >> 10;
                int rem   = col & 1023;
                int h = rem >> 6, d = rem & 63;
                long idx = (((long)(b * H_ + h)) * N_ + n) * D_ + d;
                float a = acc[mt][nt][r];
                u16 val = f2bf(a);
                if (which == 0) {
                    q[idx]  = val;
                    qs[idx] = f2bf(a * SC_LOG2E);
                } else {
                    u16* dst = (which == 1) ? k : v;
                    dst[idx] = val;
                }
            }
        }
    }
}

// ---------------------------------------------------------------------------
// Kernel 1b: vb [bh][n][d] -> vT [bh][d][n] (LDS transpose, XOR swizzle)
// ---------------------------------------------------------------------------
__global__ __launch_bounds__(256) void vt_transpose(
    const u16* __restrict__ vb, u16* __restrict__ vT) {
    __shared__ u16 T[64 * 72];
    const int bh = blockIdx.y;
    const int n0 = blockIdx.x * 64;
    const int t  = threadIdx.x;
    const int jj = t >> 3, kg = (t & 7) * 8;
    #pragma unroll
    for (int i = 0; i < 2; i++) {
        int j = jj + i * 32;
        short8 vv = *(const short8*)&vb[(((long)bh * N_ + n0 + j) << 6) + kg];
        u16* vp = (u16*)&vv;
        int jc = j ^ kg;
        #pragma unroll
        for (int c = 0; c < 8; c++) T[(kg + c) * 72 + jc] = vp[c];
    }
    __syncthreads();
    const int d = t >> 2, sg = (t & 3) * 16, xr = d & 56;
    short8 a0 = *(const short8*)&T[d * 72 + (sg ^ xr)];
    short8 a1 = *(const short8*)&T[d * 72 + ((sg + 8) ^ xr)];
    u16* dst = vT + ((long)bh * 64 + d) * 2048 + n0 + sg;
    *(short8*)dst       = a0;
    *(short8*)(dst + 8) = a1;
}

// ---------------------------------------------------------------------------
// Kernel 2: out_M = beta*M, out_Z = beta*Z
// ---------------------------------------------------------------------------
__global__ __launch_bounds__(256) void init_mz(
    const float* __restrict__ M, const float* __restrict__ Z,
    const float* __restrict__ beta_lin,
    float* __restrict__ outM, float* __restrict__ outZ) {
    float beta = 1.f / (1.f + __expf(-beta_lin[0]));
    beta = fminf(fmaxf(beta, 0.9f), 0.999f);
    int i = blockIdx.x * 256 + threadIdx.x;
    if (i < M_ELEMS) outM[i] = beta * M[i];
    if (i < Z_ELEMS) outZ[i] = beta * Z[i];
}

// ---------------------------------------------------------------------------
// Kernel 3: linear-attention branch via MFMA (unchanged).
// ---------------------------------------------------------------------------
__global__ __launch_bounds__(256) void linear_mfma(
    const u16* __restrict__ qg, const u16* __restrict__ kg_,
    const u16* __restrict__ vTg, const float* __restrict__ Mg,
    const float* __restrict__ Zg, const float* __restrict__ beta_gate,
    float* __restrict__ outA, float* __restrict__ outM, float* __restrict__ outZ) {
    __shared__ u16 MTz[80 * 72];
    __shared__ u16 sqsh[64 * 72];
    __shared__ u16 sksh[64 * 72];
    __shared__ u16 skT[64 * 72];
    __shared__ u16 vT[64 * 72];
    __shared__ u16 vmT[80 * 72];
    __shared__ float dks[64];

    const int bh = blockIdx.y, b = bh >> 4, h = bh & 15;
    const int t = threadIdx.x, w = t >> 6, lane = t & 63;
    const int quad = lane >> 4, l16 = lane & 15;
    const long bhN = (long)bh * N_;

    #pragma unroll
    for (int i = 0; i < 4; i++) {
        int d  = (t >> 4) + i * 16;
        int c4 = (t & 15) * 4;
        float4 f = *(const float4*)&Mg[bh * 4096 + d * 64 + c4];
        MTz[(c4 + 0) * 72 + d] = f2bf(f.x);
        MTz[(c4 + 1) * 72 + d] = f2bf(f.y);
        MTz[(c4 + 2) * 72 + d] = f2bf(f.z);
        MTz[(c4 + 3) * 72 + d] = f2bf(f.w);
    }
    if (t < 64) {
        MTz[64 * 72 + t] = f2bf(Zg[bh * 64 + t]);
        vmT[64 * 72 + t] = f2bf(1.0f);
    }
    for (int e = t; e < 15 * 72; e += 256) {
        MTz[65 * 72 + e] = 0;
        vmT[65 * 72 + e] = 0;
    }
    if (t >= 64 && t < 72) { MTz[64 * 72 + t] = 0; vmT[64 * 72 + t] = 0; }

    const float g = 1.f / (1.f + __expf(-beta_gate[h]));

    f32x4 macc[5] = {};

    const int jj = t >> 3;
    const int kgp = (t & 7) * 8;
    const int srow = t >> 2;
    const int sg   = (t & 3) * 16;

    for (int c0 = 0; c0 < 256; c0 += 64) {
        const int n0c = blockIdx.x * 256 + c0;
        __syncthreads();

        #pragma unroll
        for (int i = 0; i < 2; i++) {
            int j = jj + i * 32;
            long gb = ((bhN + n0c + j) << 6) + kgp;
            short8 q8 = sig8(*(const short8*)&qg[gb]);
            short8 k8 = sig8(*(const short8*)&kg_[gb]);
            *(short8*)&sqsh[j * 72 + kgp] = q8;
            *(short8*)&sksh[j * 72 + kgp] = k8;
            u16* kp = (u16*)&k8;
            int jc = j ^ kgp;
            #pragma unroll
            for (int c = 0; c < 8; c++) skT[(kgp + c) * 72 + jc] = kp[c];
        }
        {
            const u16* vp = vTg + ((long)bh * 64 + srow) * 2048 + n0c + sg;
            *(short8*)&vT[srow * 72 + sg]     = *(const short8*)vp;
            *(short8*)&vT[srow * 72 + sg + 8] = *(const short8*)(vp + 8);
        }
        __syncthreads();

        // --- MFMA1: A_raw = sq @ MTz ---
        {
            short8 a0 = *(const short8*)&sqsh[(w * 16 + l16) * 72 + quad * 8];
            short8 a1 = *(const short8*)&sqsh[(w * 16 + l16) * 72 + 32 + quad * 8];
            f32x4 am[5];
            #pragma unroll
            for (int ct = 0; ct < 5; ct++) {
                short8 b0 = *(const short8*)&MTz[(ct * 16 + l16) * 72 + quad * 8];
                short8 b1 = *(const short8*)&MTz[(ct * 16 + l16) * 72 + 32 + quad * 8];
                f32x4 acc = {};
                acc = __builtin_amdgcn_mfma_f32_16x16x32_bf16(a0, b0, acc, 0, 0, 0);
                acc = __builtin_amdgcn_mfma_f32_16x16x32_bf16(a1, b1, acc, 0, 0, 0);
                am[ct] = acc;
            }
            #pragma unroll
            for (int r = 0; r < 4; r++) {
                float dq  = __shfl(am[4][r], lane & 48, 64);
                float inv = __builtin_amdgcn_rcpf(dq);
                int n = n0c + w * 16 + quad * 4 + r;
                long row = ((long)(b * N_ + n)) * INNER_ + h * 64;
                #pragma unroll
                for (int ct = 0; ct < 4; ct++)
                    outA[row + ct * 16 + l16] = g * am[ct][r] * inv;
            }
        }

        // --- MFMA2: momentT = MTz @ sk ---
        f32x4 mt_[4];
        {
            short8 a0 = *(const short8*)&MTz[(w * 16 + l16) * 72 + quad * 8];
            short8 a1 = *(const short8*)&MTz[(w * 16 + l16) * 72 + 32 + quad * 8];
            #pragma unroll
            for (int ct = 0; ct < 4; ct++) {
                short8 b0 = *(const short8*)&sksh[(ct * 16 + l16) * 72 + quad * 8];
                short8 b1 = *(const short8*)&sksh[(ct * 16 + l16) * 72 + 32 + quad * 8];
                f32x4 acc = {};
                acc = __builtin_amdgcn_mfma_f32_16x16x32_bf16(a0, b0, acc, 0, 0, 0);
                acc = __builtin_amdgcn_mfma_f32_16x16x32_bf16(a1, b1, acc, 0, 0, 0);
                mt_[ct] = acc;
            }
            short8 z0 = *(const short8*)&MTz[(64 + l16) * 72 + quad * 8];
            short8 z1 = *(const short8*)&MTz[(64 + l16) * 72 + 32 + quad * 8];
            short8 b0 = *(const short8*)&sksh[(w * 16 + l16) * 72 + quad * 8];
            short8 b1 = *(const short8*)&sksh[(w * 16 + l16) * 72 + 32 + quad * 8];
            f32x4 acc = {};
            acc = __builtin_amdgcn_mfma_f32_16x16x32_bf16(z0, b0, acc, 0, 0, 0);
            acc = __builtin_amdgcn_mfma_f32_16x16x32_bf16(z1, b1, acc, 0, 0, 0);
            if (quad == 0) dks[w * 16 + l16] = __builtin_amdgcn_rcpf(acc[0]);
        }
        __syncthreads();

        // --- vmT = vT - momentT/dk (bf16) ---
        #pragma unroll
        for (int ct = 0; ct < 4; ct++) {
            float invdk = dks[ct * 16 + l16];
            #pragma unroll
            for (int r = 0; r < 4; r++) {
                int vd = w * 16 + quad * 4 + r;
                float vv = bf2f(vT[vd * 72 + ct * 16 + l16]);
                vmT[vd * 72 + ct * 16 + l16] = f2bf(vv - mt_[ct][r] * invdk);
            }
        }
        __syncthreads();

        // --- MFMA3: Macc += skT @ [vm | 1] ---
        {
            int drow = w * 16 + l16, xr = drow & 56;
            short8 a0 = *(const short8*)&skT[drow * 72 + ((quad * 8) ^ xr)];
            short8 a1 = *(const short8*)&skT[drow * 72 + ((32 + quad * 8) ^ xr)];
            #pragma unroll
            for (int ct = 0; ct < 5; ct++) {
                short8 b0 = *(const short8*)&vmT[(ct * 16 + l16) * 72 + quad * 8];
                short8 b1 = *(const short8*)&vmT[(ct * 16 + l16) * 72 + 32 + quad * 8];
                macc[ct] = __builtin_amdgcn_mfma_f32_16x16x32_bf16(a0, b0, macc[ct], 0, 0, 0);
                macc[ct] = __builtin_amdgcn_mfma_f32_16x16x32_bf16(a1, b1, macc[ct], 0, 0, 0);
            }
        }
    }

    #pragma unroll
    for (int ct = 0; ct < 4; ct++)
        #pragma unroll
        for (int r = 0; r < 4; r++) {
            int d = w * 16 + quad * 4 + r;
            atomicAdd(&outM[bh * 4096 + d * 64 + ct * 16 + l16], macc[ct][r]);
        }
    if (l16 == 0)
        #pragma unroll
        for (int r = 0; r < 4; r++)
            atomicAdd(&outZ[bh * 64 + w * 16 + quad * 4 + r], macc[4][r]);
}

// ---------------------------------------------------------------------------
// Kernel 4: flash attention. Banked structure + register-resident P:
// K is staged into LDS with PERMUTED row placement (sigma = kperm^-1 per
// 32-key block), so compute reads consecutive rows (the verified 2-way
// pattern) yet row l16 holds key kperm(l16) -> S^T C/D frag IS the PV
// A-frag (r7-verified identity). No P LDS round-trip; Ps deleted (18 KB).
// ---------------------------------------------------------------------------
__global__ __launch_bounds__(256) void flash_mfma(
    const u16* __restrict__ qsb, const u16* __restrict__ kb,
    const u16* __restrict__ vTg, const float* __restrict__ beta_gate,
    float* __restrict__ outA) {
    __shared__ u16 Ks[64 * 72];        // permuted-row K tile [row][d]
    __shared__ u16 Vt[64 * 72];        // [d][key] straight

    const int bh = blockIdx.y, b = bh >> 4, h = bh & 15;
    const int n0 = blockIdx.x * 128;
    const int t = threadIdx.x, w = t >> 6, lane = t & 63;
    const int quad = lane >> 4, l16 = lane & 15;
    const long bhN = (long)bh * N_;

    const int srow = t >> 2;           // 0..63 : key offset within tile
    const int sg   = (t & 3) * 16;
    // permuted LDS row for K: sigma(j) = ((j&4)<<2) + ((j>>3)<<2) + (j&3), per 32-block
    const int jloc = srow & 31;
    const int krow = (srow & 32) + ((jloc & 4) << 2) + ((jloc >> 3) << 2) + (jloc & 3);

    const u16* kbase  = kb + (bhN << 6);
    const u16* vtbase = vTg + (long)bh * 64 * 2048;

    short8 qf[2][2];
    #pragma unroll
    for (int mi = 0; mi < 2; mi++) {
        long qrow = bhN + n0 + w * 32 + mi * 16 + l16;
        qf[mi][0] = *(const short8*)&qsb[(qrow << 6) + quad * 8];
        qf[mi][1] = *(const short8*)&qsb[(qrow << 6) + 32 + quad * 8];
    }

    const short8 onesf = {0x3F80, 0x3F80, 0x3F80, 0x3F80,
                          0x3F80, 0x3F80, 0x3F80, 0x3F80};  // bf16 1.0 x8

    // prefetch tile 0
    short8 kr0, kr1, vr0, vr1;
    {
        const u16* kp = kbase + ((long)srow << 6) + sg;
        kr0 = *(const short8*)kp;
        kr1 = *(const short8*)(kp + 8);
        const u16* vp = vtbase + (long)srow * 2048 + sg;
        vr0 = *(const short8*)vp;
        vr1 = *(const short8*)(vp + 8);
    }

    f32x4 of[2][4] = {};
    f32x4 ol[2] = {};

    for (int j0 = 0; j0 < N_; j0 += 64) {
        __syncthreads();
        *(short8*)&Ks[krow * 72 + sg]     = kr0;
        *(short8*)&Ks[krow * 72 + sg + 8] = kr1;
        *(short8*)&Vt[srow * 72 + sg]     = vr0;
        *(short8*)&Vt[srow * 72 + sg + 8] = vr1;
        __syncthreads();

        if (j0 + 64 < N_) {   // prefetch next tile during compute
            const u16* kp = kbase + ((long)(j0 + 64 + srow) << 6) + sg;
            kr0 = *(const short8*)kp;
            kr1 = *(const short8*)(kp + 8);
            const u16* vp = vtbase + (long)srow * 2048 + j0 + 64 + sg;
            vr0 = *(const short8*)vp;
            vr1 = *(const short8*)(vp + 8);
        }

        #pragma unroll
        for (int g = 0; g < 2; g++) {
            const int rb = g * 32;
            // A-frag rows l16 -> keys rb+kperm(l16) (st0); rows 16+l16 -> +4 (st1)
            short8 kA0 = *(const short8*)&Ks[(rb + l16) * 72 + quad * 8];
            short8 kA1 = *(const short8*)&Ks[(rb + l16) * 72 + 32 + quad * 8];
            short8 kB0 = *(const short8*)&Ks[(rb + 16 + l16) * 72 + quad * 8];
            short8 kB1 = *(const short8*)&Ks[(rb + 16 + l16) * 72 + 32 + quad * 8];
            // V B-frags: B[k=key quad*8+j][n=d l16], contiguous keys
            short8 vf[4];
            #pragma unroll
            for (int nt = 0; nt < 4; nt++)
                vf[nt] = *(const short8*)&Vt[(nt * 16 + l16) * 72 + rb + quad * 8];

            #pragma unroll
            for (int mi = 0; mi < 2; mi++) {
                f32x4 st0 = {}, st1 = {};
                st0 = __builtin_amdgcn_mfma_f32_16x16x32_bf16(kA0, qf[mi][0], st0, 0, 0, 0);
                st0 = __builtin_amdgcn_mfma_f32_16x16x32_bf16(kA1, qf[mi][1], st0, 0, 0, 0);
                st1 = __builtin_amdgcn_mfma_f32_16x16x32_bf16(kB0, qf[mi][0], st1, 0, 0, 0);
                st1 = __builtin_amdgcn_mfma_f32_16x16x32_bf16(kB1, qf[mi][1], st1, 0, 0, 0);
                // lane holds S[key rb+quad*8+r][Q-row l16] (st0 r=0..3, st1 +4)
                float p0 = __builtin_amdgcn_exp2f(st0[0]);
                float p1 = __builtin_amdgcn_exp2f(st0[1]);
                float p2 = __builtin_amdgcn_exp2f(st0[2]);
                float p3 = __builtin_amdgcn_exp2f(st0[3]);
                float p4 = __builtin_amdgcn_exp2f(st1[0]);
                float p5 = __builtin_amdgcn_exp2f(st1[1]);
                float p6 = __builtin_amdgcn_exp2f(st1[2]);
                float p7 = __builtin_amdgcn_exp2f(st1[3]);
                // pack to PV A-frag: A[m=l16][k=quad*8+j] == P — layout identity
                short8 af;
                unsigned int* au = (unsigned int*)&af;
                au[0] = __builtin_amdgcn_perm(__float_as_uint(p1), __float_as_uint(p0),
                                              0x07060302u);
                au[1] = __builtin_amdgcn_perm(__float_as_uint(p3), __float_as_uint(p2),
                                              0x07060302u);
                au[2] = __builtin_amdgcn_perm(__float_as_uint(p5), __float_as_uint(p4),
                                              0x07060302u);
                au[3] = __builtin_amdgcn_perm(__float_as_uint(p7), __float_as_uint(p6),
                                              0x07060302u);
                ol[mi] = __builtin_amdgcn_mfma_f32_16x16x32_bf16(af, onesf, ol[mi], 0, 0, 0);
                #pragma unroll
                for (int nt = 0; nt < 4; nt++)
                    of[mi][nt] = __builtin_amdgcn_mfma_f32_16x16x32_bf16(
                        af, vf[nt], of[mi][nt], 0, 0, 0);
            }
        }
    }

    const float g  = 1.f / (1.f + __expf(-beta_gate[h]));
    const float gi = 1.f - g;
    #pragma unroll
    for (int mi = 0; mi < 2; mi++) {
        #pragma unroll
        for (int r = 0; r < 4; r++) {
            // ol[mi][r] = l for Q-row mi*16+quad*4+r (C/D row = quad*4+r)
            float sc = gi / ol[mi][r];
            int n = n0 + w * 32 + mi * 16 + quad * 4 + r;
            #pragma unroll
            for (int nt = 0; nt < 4; nt++) {
                long idx = ((long)(b * N_ + n)) * INNER_ + h * 64 + nt * 16 + l16;
                outA[idx] += sc * of[mi][nt][r];
            }
        }
    }
}

extern "C" void kernel_launch(void* const* d_in, const int* in_sizes, int n_in,
                              void* d_out, int out_size, void* d_ws, size_t ws_size,
                              hipStream_t stream) {
    const float* x         = (const float*)d_in[0];
    const float* M         = (const float*)d_in[1];
    const float* Z         = (const float*)d_in[2];
    const float* W         = (const float*)d_in[3];
    const float* beta_lin  = (const float*)d_in[4];
    const float* beta_gate = (const float*)d_in[5];

    float* out  = (float*)d_out;
    float* outA = out;
    float* outM = out + A_ELEMS;
    float* outZ = out + A_ELEMS + M_ELEMS;

    u16* xb = (u16*)d_ws;                         // [8192][1024]
    u16* Wt = xb + (size_t)8192 * 1024;           // [3072][1024]
    u16* qb = Wt + (size_t)3072 * 1024;           // [bh][n][d]
    u16* kb = qb + (size_t)BH_ * N_ * D_;         // [bh][n][d]
    u16* vb = kb + (size_t)BH_ * N_ * D_;         // [bh][n][d]
    u16* vt = vb + (size_t)BH_ * N_ * D_;         // [bh][d][n]
    u16* qs = vt + (size_t)BH_ * N_ * D_;         // [bh][n][d] pre-scaled q

    cvt_x<<<dim3(A_ELEMS / 1024), 256, 0, stream>>>(x, xb);
    cvt_w<<<dim3(48, 16), 256, 0, stream>>>(W, Wt);
    qkv_mfma<<<dim3(24, 64), 256, 0, stream>>>(xb, Wt, qb, kb, vb, qs);
    vt_transpose<<<dim3(N_ / 64, BH_), 256, 0, stream>>>(vb, vt);
    init_mz<<<dim3((M_ELEMS + 255) / 256), 256, 0, stream>>>(M, Z, beta_lin, outM, outZ);
    linear_mfma<<<dim3(8, BH_), 256, 0, stream>>>(qb, kb, vt, M, Z, beta_gate,
                                                  outA, outM, outZ);
    flash_mfma<<<dim3(N_ / 128, BH_), 256, 0, stream>>>(qs, kb, vt, beta_gate, outA);
}